// Round 9
// baseline (4972.335 us; speedup 1.0000x reference)
//
#include <hip/hip_runtime.h>
#include <stdint.h>
#include <stdio.h>

// ---------------------------------------------------------------------------
// DilatedSparseRnnStack, round 13: r10 (last green, 4387us) + ONLY provably
// hazard-free prefetches. r11/r12's cross-barrier RING prefetch failed
// correctness twice (cause not found by audit) -> abandoned. Safe set:
//  - wob: POST-layer weight fragments prefetched from LDS one window early.
//    Weights are CONSTANT after startup -> zero hazard. Cuts 8 ds_reads from
//    the serial POST path.
//  - x prefetch: x(t) frags for preL2 loaded in window A; x(t+1) frags for
//    fullL0 loaded in window B. x is a read-only input -> zero hazard.
//  - s_sleep(1) restored in waitbar poll (reduce L2 flag-line contention).
// Ring (bufH) loads stay IN-WINDOW exactly as green r10. touchx stays deleted.
// Schedule per step t (3 barriers):
//   A: postL3(t-1)[wob] | win: preL1(t) + dc1 + loadX(xa2,t) + wob<-W1
//   B: postL1(t)[wob]   | win: preL2(t,xa2) + dc2 + epi(t-1) + loadX(xa0,t+1) + wob<-W2
//   C: postL2(t)[wob]   | win: preL3(t) + dc3 + fullL0(t+1,xa0) + wob<-W3
// ---------------------------------------------------------------------------

typedef __attribute__((ext_vector_type(8))) short short8;
typedef __attribute__((ext_vector_type(4))) float f32x4;

#define DEVINL static __device__ __forceinline__

constexpr int TT = 256, BBATCH = 1024, INW = 64, HSW = 128, OSW = 128, NO = 8;
constexpr int ROWS = 128;                 // batch rows per cluster

constexpr int KLa[4]   = {192, 384, 448, 384};   // layer-0 dH folded: 320 -> 192
constexpr int DILa[4]  = {1, 3, 6, 12};
constexpr int PERa[4]  = {2, 4, 7, 13};   // h ring period = dil+1
// tiled weight layout: per (kt, half) a 1KB tile of 512 ushorts [lm][quad][8]
constexpr int WOFFa[4] = {0, 6144, 18432, 32768};   // ushort offsets
constexpr int WBYTES   = 90112;                     // 32 rows x 1408 k x 2B

constexpr int BIAS_B  = WBYTES;                    // 90,112
constexpr int WOUT_B  = BIAS_B + 512;              // 90,624
constexpr int WSTR    = 129;                       // wout pad
constexpr int BOUT_B  = WOUT_B + 8 * WSTR * 4;     // 94,752
constexpr int C3_B    = BOUT_B + 32;               // 94,784
constexpr int LDS_BYTES = C3_B + 12 * 256 * 16;    // 143,936 (<= 160 KiB)

// workspace layout (bytes)
//   [0,4096)     barrier flags: cluster c, wave w -> ws + c*512 + w*128, 32 words
//   [4096,4608)  per-XCD rank counters (c*64)
constexpr size_t WSBASE    = 8192;
constexpr size_t BH_OFF[4] = {0, 65536, 196608, 425984}; // h rings (P_l slots of 128x128 bf16)
constexpr size_t OUTB_OFF  = 851968;                     // 4 x 128x128 bf16 (single-buffered)
constexpr size_t CB_OFF    = 983040;                     // C rings: layers 1,2
constexpr size_t C1_SZ     = 32 * 3 * 256 * 16;          // 393,216
constexpr size_t C2_SZ     = 32 * 6 * 256 * 16;          // 786,432
constexpr size_t CLSZ      = CB_OFF + C1_SZ + C2_SZ;     // 2,162,688 (~2.1 MB)
constexpr size_t WS_NEED   = WSBASE + 8 * CLSZ;          // ~17.3 MB

__host__ __device__ constexpr int seg_type(int L, int k) {
  // 0 = x (fp32), 1 = prev-layer out, 2 = prevH, 3 = dH
  if (L == 0) return k < 64 ? 0 : 2;                    // dH folded into prevH
  if (L == 1) return k < 128 ? 1 : (k < 256 ? 2 : 3);
  if (L == 2) return k < 128 ? 1 : (k < 192 ? 0 : (k < 320 ? 2 : 3));
  return k < 128 ? 1 : (k < 256 ? 2 : 3);
}
__host__ __device__ constexpr int seg_start(int L, int k) {
  if (L == 0) return k < 64 ? 0 : 64;
  if (L == 1) return k < 128 ? 0 : (k < 256 ? 128 : 256);
  if (L == 2) return k < 128 ? 0 : (k < 192 ? 128 : (k < 320 ? 192 : 320));
  return k < 128 ? 0 : (k < 256 ? 128 : 256);
}

template <int N> struct IC { static constexpr int value = N; };

DEVINL unsigned short f2bf(float f) {        // RNE fp32 -> bf16
  union { float f; uint32_t u; } v; v.f = f;
  return (unsigned short)((v.u + 0x7FFFu + ((v.u >> 16) & 1u)) >> 16);
}
DEVINL float bf2f(unsigned short h) {
  union { uint32_t u; float f; } v; v.u = ((uint32_t)h) << 16;
  return v.f;
}
DEVINL float sigm(float x)  { return 1.0f / (1.0f + __expf(-x)); }
DEVINL float tanh_(float x) { return 1.0f - 2.0f / (__expf(2.0f * x) + 1.0f); }

DEVINL short8 zero_s8() { short8 v; for (int i = 0; i < 8; i++) v[i] = 0; return v; }
DEVINL f32x4  zero_f4() { f32x4  v; for (int i = 0; i < 4; i++) v[i] = 0.f; return v; }

DEVINL f32x4 mfma16(short8 a, short8 b, f32x4 c) {
  return __builtin_amdgcn_mfma_f32_16x16x32_bf16(a, b, c, 0, 0, 0);
}

DEVINL short8 pk8(f32x4 a, f32x4 b) {        // 2x f32x4 -> bf16x8 fragment
  short8 r;
  r[0] = (short)f2bf(a[0]); r[1] = (short)f2bf(a[1]);
  r[2] = (short)f2bf(a[2]); r[3] = (short)f2bf(a[3]);
  r[4] = (short)f2bf(b[0]); r[5] = (short)f2bf(b[1]);
  r[6] = (short)f2bf(b[2]); r[7] = (short)f2bf(b[3]);
  return r;
}
DEVINL short8 ld8f(const float* p) {
  return pk8(*(const f32x4*)p, *(const f32x4*)(p + 4));
}

__global__ void __launch_bounds__(256, 1)
rnn_stack_kernel(const float* __restrict__ x,
                 const float* __restrict__ W0, const float* __restrict__ b0,
                 const float* __restrict__ W1, const float* __restrict__ b1,
                 const float* __restrict__ W2, const float* __restrict__ b2,
                 const float* __restrict__ W3, const float* __restrict__ b3,
                 const float* __restrict__ Wout, const float* __restrict__ bout,
                 float* __restrict__ yout, char* __restrict__ ws)
{
  extern __shared__ char smem[];
  unsigned short* wlds = (unsigned short*)smem;
  float* biasl = (float*)(smem + BIAS_B);
  float* woutl = (float*)(smem + WOUT_B);
  float* boutl = (float*)(smem + BOUT_B);
  float* c3l   = (float*)(smem + C3_B);     // [(slot*256 + tid)*4] f32 (lane-private)

  const int tid = threadIdx.x;

  // ---- runtime cluster formation: c = physical XCD, g = rank on that XCD ----
  __shared__ unsigned s_cg;
  if (tid == 0) {
    unsigned xcc;
    asm volatile("s_getreg_b32 %0, hwreg(HW_REG_XCC_ID)" : "=s"(xcc));
    xcc &= 7u;
    unsigned rank = __hip_atomic_fetch_add(
        (unsigned*)(ws + 4096 + (size_t)xcc * 64), 1u,
        __ATOMIC_RELAXED, __HIP_MEMORY_SCOPE_AGENT);
    s_cg = (xcc << 8) | (rank & 31u);
  }
  __syncthreads();
  const int c = __builtin_amdgcn_readfirstlane((int)(s_cg >> 8));
  const int g = __builtin_amdgcn_readfirstlane((int)(s_cg & 255));

  char* cb = ws + WSBASE + (size_t)c * CLSZ;
  unsigned short* bufH[4];
  unsigned short* outb[4];
#pragma unroll
  for (int l = 0; l < 4; l++) {
    bufH[l] = (unsigned short*)(cb + BH_OFF[l]);
    outb[l] = (unsigned short*)(cb + OUTB_OFF + (size_t)l * ROWS * OSW * 2);
  }
  float* bufC1 = (float*)(cb + CB_OFF + (size_t)g * (3 * 256 * 16));
  float* bufC2 = (float*)(cb + CB_OFF + C1_SZ + (size_t)g * (6 * 256 * 16));

  // ---- startup: weights -> tiled LDS (bf16); layer-0 dH block folded ----
  {
    const float* Wsrc[4] = {W0, W1, W2, W3};
    const float* bsrc[4] = {b0, b1, b2, b3};
    for (int l = 0; l < 4; l++) {
      const int K = KLa[l];
      const int Ksrc = (l == 0) ? 320 : K;             // W0 rows are length 320
      unsigned short* base = wlds + WOFFa[l];
      for (int n = 0; n < 32; n++) {
        const int grow = (n >> 3) * 256 + g * 8 + (n & 7);   // gate*SS + jglob
        const float* src = Wsrc[l] + (size_t)grow * Ksrc;
        for (int k = tid; k < K; k += 256) {
          float v = src[k];
          if (l == 0 && k >= 64) v += src[k + 128];    // fold W_dH into W_prevH
          base[((k >> 5) * 2 + (n >> 4)) * 512 + (n & 15) * 32 +
               ((k >> 3) & 3) * 8 + (k & 7)] = f2bf(v);
        }
      }
      if (tid < 32) biasl[l * 32 + tid] = bsrc[l][(tid >> 3) * 256 + g * 8 + (tid & 7)];
    }
    for (int i = tid; i < 8 * 128; i += 256) woutl[(i >> 7) * WSTR + (i & 127)] = Wout[i];
    if (tid < 8) boutl[tid] = bout[tid];
  }
  __syncthreads();           // the ONLY wg-wide sync; waves decouple after this

  const int wv = tid >> 6, lane = tid & 63, lm = lane & 15, quad = lane >> 4;
  const int m0 = wv * 32;          // wave's private 32 batch rows (2 M-tiles)
  const bool hi = lm >= 8;
  const int j = lm & 7;            // this lane's j-column (0..7)
  const int mrow = m0 + (hi ? 16 : 0) + quad * 4;   // first of this lane's 4 rows

  // per-wave barrier flag block: 32 words (one per WG) for (cluster c, wave wv)
  unsigned* flg = (unsigned*)(ws + (size_t)c * 512 + (size_t)wv * 128);

  f32x4 pc[4];                     // prevC (4 rows x this lane's j), per layer
#pragma unroll
  for (int l = 0; l < 4; l++) pc[l] = zero_f4();

  f32x4 dc1 = zero_f4(), dc2 = zero_f4(), dc3 = zero_f4();

  // hazard-free prefetch state (constant LDS weights / read-only x)
  short8 wob[2][4];                // next POST's ob-weight fragments
  short8 xa2[2][2];                // x(t) frags for preL2 (kt 4..5)
  short8 xa0[2][2];                // x(t+1) frags for fullL0 (kt 0..1)

  auto arrive = [&](unsigned ep) {
    asm volatile("s_waitcnt vmcnt(0)" ::: "memory");   // publish stores in L2
    if (lane == 0)
      __hip_atomic_store(flg + g, ep, __ATOMIC_RELAXED, __HIP_MEMORY_SCOPE_AGENT);
  };
  auto waitbar = [&](unsigned ep) {
    asm volatile("" ::: "memory");
    for (;;) {
      unsigned v = __hip_atomic_load(flg + (lane & 31), __ATOMIC_RELAXED,
                                     __HIP_MEMORY_SCOPE_AGENT);
      if (__all((int)(v >= ep))) break;
      __builtin_amdgcn_s_sleep(1);
    }
    asm volatile("buffer_inv sc0" ::: "memory");   // L1 invalidate (XCD acquire)
  };

  // ---- x prefetch (read-only input: zero-hazard) ----
  auto loadX = [&](short8 (&xa)[2][2], int t) {
    if (t >= TT) return;
    const float* xb = x + ((size_t)t * BBATCH + (size_t)c * ROWS) * INW;
#pragma unroll
    for (int kk = 0; kk < 2; kk++) {
      const float* p = xb + (size_t)(m0 + lm) * INW + kk * 32 + quad * 8;
      xa[0][kk] = ld8f(p);
      xa[1][kk] = ld8f(p + 16 * INW);
    }
  };

  // ---- next POST's ob-weight fragments (constant LDS: zero-hazard) ----
  auto loadWob = [&](int L) {
    const unsigned short* wl = wlds + WOFFa[L];
#pragma unroll
    for (int kt = 0; kt < 4; kt++) {
      wob[0][kt] = *(const short8*)(wl + (kt * 2 + 0) * 512 + lm * 32 + quad * 8);
      wob[1][kt] = *(const short8*)(wl + (kt * 2 + 1) * 512 + lm * 32 + quad * 8);
    }
  };

  // ---- cell + publish from finished accumulators (r6-verbatim) ----
  auto cellpub = [&](auto Lc, int t, f32x4& A00, f32x4& A01, f32x4& A10, f32x4& A11) {
    constexpr int L = decltype(Lc)::value;
    constexpr int DL = DILa[L];
    constexpr int P = PERa[L];
    f32x4 s00, s01, s10, s11;
#pragma unroll
    for (int r = 0; r < 4; r++) {
      s00[r] = __shfl_xor(A00[r], 8);
      s01[r] = __shfl_xor(A01[r], 8);
      s10[r] = __shfl_xor(A10[r], 8);
      s11[r] = __shfl_xor(A11[r], 8);
    }
    f32x4 G0, G1, G2, G3;
#pragma unroll
    for (int r = 0; r < 4; r++) {
      G0[r] = hi ? s10[r] : A00[r];
      G1[r] = hi ? A10[r] : s00[r];
      G2[r] = hi ? s11[r] : A01[r];
      G3[r] = hi ? A11[r] : s01[r];
    }
    const f32x4 pcv = pc[L];
    f32x4 dC = zero_f4();
    if constexpr (L == 1) dC = dc1;
    if constexpr (L == 2) dC = dc2;
    if constexpr (L == 3) dC = dc3;
    f32x4 nC, wh;
#pragma unroll
    for (int q = 0; q < 4; q++) {
      const float fg = sigm(G0[q]);        // bias & +1.0 already in acc init
      const float cd = tanh_(G1[q]);
      const float og = sigm(G3[q]);
      float wc;
      if constexpr (L == 0) {
        wc = pcv[q];                       // dil=1: alpha*prevC+(1-alpha)*prevC
      } else {
        const float al = sigm(G2[q]);
        wc = (t >= DL) ? (al * pcv[q] + (1.0f - al) * dC[q]) : pcv[q];
      }
      const float nc = (t >= 1) ? (fg * wc + (1.0f - fg) * cd) : cd;
      nC[q] = nc;
      wh[q] = og * nc;
    }
    if constexpr (L == 1) *(f32x4*)(bufC1 + ((size_t)(t % 3) * 256 + tid) * 4) = nC;
    if constexpr (L == 2) *(f32x4*)(bufC2 + ((size_t)(t % 6) * 256 + tid) * 4) = nC;
    if constexpr (L == 3) *(f32x4*)(c3l + ((size_t)(t % 12) * 256 + tid) * 4) = nC;
    pc[L] = nC;
    const int jg = g * 8 + j;
#pragma unroll
    for (int r = 0; r < 4; r++) {
      const unsigned short us = f2bf(wh[r]);
      const int row = mrow + r;
      if (g < 16) outb[L][(size_t)row * OSW + jg] = us;
      else bufH[L][((size_t)(t % P) * ROWS + row) * HSW + (jg - 128)] = us;
    }
  };

  // ---- PRE (L in 1..3): acc init + non-ob segment MFMAs (rings in-window,
  //      exactly as green r10; L2's x segment consumes prefetched xa2) ----
  auto preL = [&](auto Lc, int t, f32x4& A00, f32x4& A01, f32x4& A10, f32x4& A11) {
    constexpr int L = decltype(Lc)::value;
    constexpr int NKT = KLa[L] / 32;
    constexpr int DL = DILa[L];
    constexpr int P = PERa[L];
    const unsigned short* wl = wlds + WOFFa[L];
    const float bb0 = biasl[L * 32 + lm] + (lm < 8 ? 1.0f : 0.0f);  // fg bias +1
    const float bb1 = biasl[L * 32 + 16 + lm];
    A00 = (f32x4){bb0, bb0, bb0, bb0};
    A10 = A00;
    A01 = (f32x4){bb1, bb1, bb1, bb1};
    A11 = A01;
    const unsigned short* phb =
        (t >= 1) ? bufH[L] + (size_t)((t - 1) % P) * ROWS * HSW : nullptr;
    const unsigned short* dhb =
        (t >= DL) ? bufH[L] + (size_t)((t - DL) % P) * ROWS * HSW : phb;
#pragma unroll
    for (int kt = 0; kt < NKT; kt++) {
      const int sty = seg_type(L, kt * 32);
      if (sty == 1) continue;                    // ob segments belong to POST
      const int sst = seg_start(L, kt * 32);
      const int kloc = kt * 32 - sst + quad * 8;
      short8 a0, a1;
      if (sty == 0) {
        if constexpr (L == 2) {                  // prefetched x(t) (window A)
          a0 = xa2[0][kt - 4];
          a1 = xa2[1][kt - 4];
        } else {
          a0 = zero_s8();
          a1 = zero_s8();
        }
      } else {
        const unsigned short* sb = (sty == 2) ? phb : dhb;
        if (sb) {
          const unsigned short* p = sb + (size_t)(m0 + lm) * HSW + kloc;
          a0 = *(const short8*)p;
          a1 = *(const short8*)(p + 16 * HSW);
        } else {
          a0 = zero_s8();
          a1 = zero_s8();
        }
      }
      const short8 bf0v = *(const short8*)(wl + (kt * 2 + 0) * 512 + lm * 32 + quad * 8);
      const short8 bf1v = *(const short8*)(wl + (kt * 2 + 1) * 512 + lm * 32 + quad * 8);
      A00 = mfma16(a0, bf0v, A00);
      A01 = mfma16(a0, bf1v, A01);
      A10 = mfma16(a1, bf0v, A10);
      A11 = mfma16(a1, bf1v, A11);
    }
  };

  // ---- POST (L in 1..3): ob-segment MFMAs w/ prefetched weights + cell ----
  auto postL = [&](auto Lc, int t, f32x4& A00, f32x4& A01, f32x4& A10, f32x4& A11) {
    constexpr int L = decltype(Lc)::value;
    const unsigned short* ob = outb[L - 1];
#pragma unroll
    for (int kt = 0; kt < 4; kt++) {
      const int kloc = kt * 32 + quad * 8;
      const unsigned short* p = ob + (size_t)(m0 + lm) * HSW + kloc;
      const short8 a0 = *(const short8*)p;
      const short8 a1 = *(const short8*)(p + 16 * HSW);
      A00 = mfma16(a0, wob[0][kt], A00);
      A01 = mfma16(a0, wob[1][kt], A01);
      A10 = mfma16(a1, wob[0][kt], A10);
      A11 = mfma16(a1, wob[1][kt], A11);
    }
    cellpub(Lc, t, A00, A01, A10, A11);
  };

  // ---- full L0: x from prefetched xa0; own h-ring in-window (r10 style) ----
  auto fullL0 = [&](int t) {
    if (t >= TT) return;
    f32x4 A00, A01, A10, A11;
    const unsigned short* wl = wlds + WOFFa[0];
    const float bb0 = biasl[lm] + (lm < 8 ? 1.0f : 0.0f);
    const float bb1 = biasl[16 + lm];
    A00 = (f32x4){bb0, bb0, bb0, bb0};
    A10 = A00;
    A01 = (f32x4){bb1, bb1, bb1, bb1};
    A11 = A01;
    const unsigned short* phb =
        (t >= 1) ? bufH[0] + (size_t)((t - 1) & 1) * ROWS * HSW : nullptr;
#pragma unroll
    for (int kt = 0; kt < 6; kt++) {
      const int sty = seg_type(0, kt * 32);
      const int sst = seg_start(0, kt * 32);
      const int kloc = kt * 32 - sst + quad * 8;
      short8 a0, a1;
      if (sty == 0) {
        a0 = xa0[0][kt];                         // prefetched x(t) (window B)
        a1 = xa0[1][kt];
      } else if (phb) {
        const unsigned short* p = phb + (size_t)(m0 + lm) * HSW + kloc;
        a0 = *(const short8*)p;
        a1 = *(const short8*)(p + 16 * HSW);
      } else {
        a0 = zero_s8();
        a1 = zero_s8();
      }
      const short8 bf0v = *(const short8*)(wl + (kt * 2 + 0) * 512 + lm * 32 + quad * 8);
      const short8 bf1v = *(const short8*)(wl + (kt * 2 + 1) * 512 + lm * 32 + quad * 8);
      A00 = mfma16(a0, bf0v, A00);
      A01 = mfma16(a0, bf1v, A01);
      A10 = mfma16(a1, bf0v, A10);
      A11 = mfma16(a1, bf1v, A11);
    }
    cellpub(IC<0>{}, t, A00, A01, A10, A11);
  };

  // ---- epilogue: wave computes y for its private row r = m0 + g ----
  auto epilogue = [&](int tt) {
    if (tt < 0) return;
    const int r = m0 + g;
    const unsigned short* orow = outb[3] + (size_t)r * OSW;
    const int o = lane >> 3, s = lane & 7;
    const short8 v0 = *(const short8*)(orow + s * 16);
    const short8 v1 = *(const short8*)(orow + s * 16 + 8);
    float part = 0.f;
#pragma unroll
    for (int i = 0; i < 8; i++)
      part += bf2f((unsigned short)v0[i]) * woutl[o * WSTR + s * 16 + i];
#pragma unroll
    for (int i = 0; i < 8; i++)
      part += bf2f((unsigned short)v1[i]) * woutl[o * WSTR + s * 16 + 8 + i];
    part += __shfl_down(part, 4);
    part += __shfl_down(part, 2);
    part += __shfl_down(part, 1);
    if (s == 0)
      yout[((size_t)tt * BBATCH + (size_t)c * ROWS + r) * NO + o] = part + boutl[o];
  };

  f32x4 a1_00, a1_01, a1_10, a1_11;    // L1 accumulators (windowA -> postB)
  f32x4 a2_00, a2_01, a2_10, a2_11;    // L2 accumulators (windowB -> postC)
  f32x4 a3_00, a3_01, a3_10, a3_11;    // L3 accumulators (windowC -> postA(t+1))

  // ---- prologue ----
  loadX(xa0, 0);
  fullL0(0);                           // publishes L0(0); drains at arrive(1)
  unsigned ep = 0;

  // ---- main loop: 3 phases per step ----
  for (int t = 0; t < TT; t++) {
    // === phase A: postL3(t-1) ===
    if (t > 0) postL(IC<3>{}, t - 1, a3_00, a3_01, a3_10, a3_11);
    arrive(++ep);
    {   // window A: preL1(t) + dc1 + x(t) prefetch for L2 + W1 frags
      loadX(xa2, t);
      preL(IC<1>{}, t, a1_00, a1_01, a1_10, a1_11);
      if (t >= 3) dc1 = *(const f32x4*)(bufC1 + ((size_t)(t % 3) * 256 + tid) * 4);
      loadWob(1);
    }
    waitbar(ep);
    // === phase B: postL1(t) ===
    postL(IC<1>{}, t, a1_00, a1_01, a1_10, a1_11);
    arrive(++ep);
    {   // window B: preL2(t) + dc2 + epilogue + x(t+1) prefetch for L0 + W2
      loadX(xa0, t + 1);
      preL(IC<2>{}, t, a2_00, a2_01, a2_10, a2_11);
      if (t >= 6) dc2 = *(const f32x4*)(bufC2 + ((size_t)(t % 6) * 256 + tid) * 4);
      epilogue(t - 1);
      loadWob(2);
    }
    waitbar(ep);
    // === phase C: postL2(t) ===
    postL(IC<2>{}, t, a2_00, a2_01, a2_10, a2_11);
    arrive(++ep);
    {   // window C: preL3(t) + dc3 + fullL0(t+1) + W3 frags
      preL(IC<3>{}, t, a3_00, a3_01, a3_10, a3_11);
      if (t >= 12) dc3 = *(const f32x4*)(c3l + ((size_t)(t % 12) * 256 + tid) * 4);
      fullL0(t + 1);
      loadWob(3);
    }
    waitbar(ep);
  }
  // tail: finish L3(TT-1), then final epilogue
  postL(IC<3>{}, TT - 1, a3_00, a3_01, a3_10, a3_11);
  arrive(++ep);
  waitbar(ep);
  epilogue(TT - 1);
}

extern "C" void kernel_launch(void* const* d_in, const int* in_sizes, int n_in,
                              void* d_out, int out_size, void* d_ws, size_t ws_size,
                              hipStream_t stream) {
  const float* x    = (const float*)d_in[0];
  const float* W0   = (const float*)d_in[1];
  const float* b0   = (const float*)d_in[2];
  const float* W1   = (const float*)d_in[3];
  const float* b1   = (const float*)d_in[4];
  const float* W2   = (const float*)d_in[5];
  const float* b2   = (const float*)d_in[6];
  const float* W3   = (const float*)d_in[7];
  const float* b3   = (const float*)d_in[8];
  const float* Wout = (const float*)d_in[9];
  const float* bout = (const float*)d_in[10];
  float* out = (float*)d_out;
  char* ws = (char*)d_ws;

  if (ws_size < WS_NEED) {
    fprintf(stderr, "kernel_launch: ws_size %zu < needed %zu\n", ws_size, (size_t)WS_NEED);
    return;
  }

  // zero barrier flags + rank counters (ws is poisoned 0xAA before every launch)
  hipMemsetAsync(d_ws, 0, 8192, stream);

  hipError_t e = hipFuncSetAttribute((const void*)rnn_stack_kernel,
                                     hipFuncAttributeMaxDynamicSharedMemorySize,
                                     LDS_BYTES);
  if (e != hipSuccess) fprintf(stderr, "hipFuncSetAttribute: %d\n", (int)e);

  rnn_stack_kernel<<<dim3(256), dim3(256), LDS_BYTES, stream>>>(
      x, W0, b0, W1, b1, W2, b2, W3, b3, Wout, bout, out, ws);
  e = hipGetLastError();
  if (e != hipSuccess) fprintf(stderr, "launch error: %d\n", (int)e);
}

// Round 10
// 4359.406 us; speedup vs baseline: 1.1406x; 1.1406x over previous
//
#include <hip/hip_runtime.h>
#include <stdint.h>
#include <stdio.h>

// ---------------------------------------------------------------------------
// DilatedSparseRnnStack, round 14: bit-exact r10 (last green, 4387us) with
// ONE change: the in-register cell's gate exchange uses DPP row_ror:8
// (v_mov_dpp, VALU pipe, 1cy) instead of __shfl_xor(8) (ds_bpermute, LDS
// pipe, ~100cy on the serial critical path). xor-8 within 16-lane rows ==
// row_ror:8 since (i+8)%16 == i^8. Also tests the theory that the invariant
// SQ_LDS_BANK_CONFLICT = 2.517e7 is shfl traffic (r8: 2x waves -> 5.03e7).
// r13's window-prefetch (wob/loadX/s_sleep) REGRESSED (windows are the
// critical path) -> reverted entirely. r11/r12 ring prefetch: abandoned
// (correctness, cause unfound).
// Schedule per step t (3 barriers, r10):
//   A: postL3(t-1) | win: preL1(t) + dc1
//   B: postL1(t)   | win: preL2(t) + dc2 + epilogue(t-1) + touchx(t+2)
//   C: postL2(t)   | win: preL3(t) + dc3 + fullL0(t+1)
// ---------------------------------------------------------------------------

typedef __attribute__((ext_vector_type(8))) short short8;
typedef __attribute__((ext_vector_type(4))) float f32x4;

#define DEVINL static __device__ __forceinline__

constexpr int TT = 256, BBATCH = 1024, INW = 64, HSW = 128, OSW = 128, NO = 8;
constexpr int ROWS = 128;                 // batch rows per cluster

constexpr int KLa[4]   = {192, 384, 448, 384};   // layer-0 dH folded: 320 -> 192
constexpr int DILa[4]  = {1, 3, 6, 12};
constexpr int PERa[4]  = {2, 4, 7, 13};   // h ring period = dil+1
// tiled weight layout: per (kt, half) a 1KB tile of 512 ushorts [lm][quad][8]
constexpr int WOFFa[4] = {0, 6144, 18432, 32768};   // ushort offsets
constexpr int WBYTES   = 90112;                     // 32 rows x 1408 k x 2B

constexpr int BIAS_B  = WBYTES;                    // 90,112
constexpr int WOUT_B  = BIAS_B + 512;              // 90,624
constexpr int WSTR    = 129;                       // wout pad
constexpr int BOUT_B  = WOUT_B + 8 * WSTR * 4;     // 94,752
constexpr int C3_B    = BOUT_B + 32;               // 94,784
constexpr int LDS_BYTES = C3_B + 12 * 256 * 16;    // 143,936 (<= 160 KiB)

// workspace layout (bytes)
//   [0,4096)     barrier flags: cluster c, wave w -> ws + c*512 + w*128, 32 words
//   [4096,4608)  per-XCD rank counters (c*64)
constexpr size_t WSBASE    = 8192;
constexpr size_t BH_OFF[4] = {0, 65536, 196608, 425984}; // h rings (P_l slots of 128x128 bf16)
constexpr size_t OUTB_OFF  = 851968;                     // 4 x 128x128 bf16 (single-buffered)
constexpr size_t CB_OFF    = 983040;                     // C rings: layers 1,2
constexpr size_t C1_SZ     = 32 * 3 * 256 * 16;          // 393,216
constexpr size_t C2_SZ     = 32 * 6 * 256 * 16;          // 786,432
constexpr size_t CLSZ      = CB_OFF + C1_SZ + C2_SZ;     // 2,162,688 (~2.1 MB)
constexpr size_t WS_NEED   = WSBASE + 8 * CLSZ;          // ~17.3 MB

__host__ __device__ constexpr int seg_type(int L, int k) {
  // 0 = x (fp32), 1 = prev-layer out, 2 = prevH, 3 = dH
  if (L == 0) return k < 64 ? 0 : 2;                    // dH folded into prevH
  if (L == 1) return k < 128 ? 1 : (k < 256 ? 2 : 3);
  if (L == 2) return k < 128 ? 1 : (k < 192 ? 0 : (k < 320 ? 2 : 3));
  return k < 128 ? 1 : (k < 256 ? 2 : 3);
}
__host__ __device__ constexpr int seg_start(int L, int k) {
  if (L == 0) return k < 64 ? 0 : 64;
  if (L == 1) return k < 128 ? 0 : (k < 256 ? 128 : 256);
  if (L == 2) return k < 128 ? 0 : (k < 192 ? 128 : (k < 320 ? 192 : 320));
  return k < 128 ? 0 : (k < 256 ? 128 : 256);
}

template <int N> struct IC { static constexpr int value = N; };

DEVINL unsigned short f2bf(float f) {        // RNE fp32 -> bf16
  union { float f; uint32_t u; } v; v.f = f;
  return (unsigned short)((v.u + 0x7FFFu + ((v.u >> 16) & 1u)) >> 16);
}
DEVINL float bf2f(unsigned short h) {
  union { uint32_t u; float f; } v; v.u = ((uint32_t)h) << 16;
  return v.f;
}
DEVINL float sigm(float x)  { return 1.0f / (1.0f + __expf(-x)); }
DEVINL float tanh_(float x) { return 1.0f - 2.0f / (__expf(2.0f * x) + 1.0f); }

DEVINL short8 zero_s8() { short8 v; for (int i = 0; i < 8; i++) v[i] = 0; return v; }
DEVINL f32x4  zero_f4() { f32x4  v; for (int i = 0; i < 4; i++) v[i] = 0.f; return v; }

DEVINL f32x4 mfma16(short8 a, short8 b, f32x4 c) {
  return __builtin_amdgcn_mfma_f32_16x16x32_bf16(a, b, c, 0, 0, 0);
}

DEVINL short8 ld8f(const float* p) {         // 8 fp32 -> bf16x8 fragment
  const f32x4 u0 = *(const f32x4*)p;
  const f32x4 u1 = *(const f32x4*)(p + 4);
  short8 r;
  r[0] = (short)f2bf(u0[0]); r[1] = (short)f2bf(u0[1]);
  r[2] = (short)f2bf(u0[2]); r[3] = (short)f2bf(u0[3]);
  r[4] = (short)f2bf(u1[0]); r[5] = (short)f2bf(u1[1]);
  r[6] = (short)f2bf(u1[2]); r[7] = (short)f2bf(u1[3]);
  return r;
}

// lane ^ 8 exchange via DPP row_ror:8 (within each 16-lane row, (i+8)%16==i^8).
// Pure VALU: replaces ds_bpermute-based __shfl_xor on the cell critical path.
DEVINL float xor8_dpp(float v) {
  int i = __builtin_bit_cast(int, v);
  i = __builtin_amdgcn_mov_dpp(i, 0x128, 0xF, 0xF, false);   // row_ror:8
  return __builtin_bit_cast(float, i);
}

__global__ void __launch_bounds__(256, 1)
rnn_stack_kernel(const float* __restrict__ x,
                 const float* __restrict__ W0, const float* __restrict__ b0,
                 const float* __restrict__ W1, const float* __restrict__ b1,
                 const float* __restrict__ W2, const float* __restrict__ b2,
                 const float* __restrict__ W3, const float* __restrict__ b3,
                 const float* __restrict__ Wout, const float* __restrict__ bout,
                 float* __restrict__ yout, char* __restrict__ ws)
{
  extern __shared__ char smem[];
  unsigned short* wlds = (unsigned short*)smem;
  float* biasl = (float*)(smem + BIAS_B);
  float* woutl = (float*)(smem + WOUT_B);
  float* boutl = (float*)(smem + BOUT_B);
  float* c3l   = (float*)(smem + C3_B);     // [(slot*256 + tid)*4] f32 (lane-private)

  const int tid = threadIdx.x;

  // ---- runtime cluster formation: c = physical XCD, g = rank on that XCD ----
  __shared__ unsigned s_cg;
  if (tid == 0) {
    unsigned xcc;
    asm volatile("s_getreg_b32 %0, hwreg(HW_REG_XCC_ID)" : "=s"(xcc));
    xcc &= 7u;
    unsigned rank = __hip_atomic_fetch_add(
        (unsigned*)(ws + 4096 + (size_t)xcc * 64), 1u,
        __ATOMIC_RELAXED, __HIP_MEMORY_SCOPE_AGENT);
    s_cg = (xcc << 8) | (rank & 31u);
  }
  __syncthreads();
  const int c = __builtin_amdgcn_readfirstlane((int)(s_cg >> 8));
  const int g = __builtin_amdgcn_readfirstlane((int)(s_cg & 255));

  char* cb = ws + WSBASE + (size_t)c * CLSZ;
  unsigned short* bufH[4];
  unsigned short* outb[4];
#pragma unroll
  for (int l = 0; l < 4; l++) {
    bufH[l] = (unsigned short*)(cb + BH_OFF[l]);
    outb[l] = (unsigned short*)(cb + OUTB_OFF + (size_t)l * ROWS * OSW * 2);
  }
  float* bufC1 = (float*)(cb + CB_OFF + (size_t)g * (3 * 256 * 16));
  float* bufC2 = (float*)(cb + CB_OFF + C1_SZ + (size_t)g * (6 * 256 * 16));

  // ---- startup: weights -> tiled LDS (bf16); layer-0 dH block folded ----
  {
    const float* Wsrc[4] = {W0, W1, W2, W3};
    const float* bsrc[4] = {b0, b1, b2, b3};
    for (int l = 0; l < 4; l++) {
      const int K = KLa[l];
      const int Ksrc = (l == 0) ? 320 : K;             // W0 rows are length 320
      unsigned short* base = wlds + WOFFa[l];
      for (int n = 0; n < 32; n++) {
        const int grow = (n >> 3) * 256 + g * 8 + (n & 7);   // gate*SS + jglob
        const float* src = Wsrc[l] + (size_t)grow * Ksrc;
        for (int k = tid; k < K; k += 256) {
          float v = src[k];
          if (l == 0 && k >= 64) v += src[k + 128];    // fold W_dH into W_prevH
          base[((k >> 5) * 2 + (n >> 4)) * 512 + (n & 15) * 32 +
               ((k >> 3) & 3) * 8 + (k & 7)] = f2bf(v);
        }
      }
      if (tid < 32) biasl[l * 32 + tid] = bsrc[l][(tid >> 3) * 256 + g * 8 + (tid & 7)];
    }
    for (int i = tid; i < 8 * 128; i += 256) woutl[(i >> 7) * WSTR + (i & 127)] = Wout[i];
    if (tid < 8) boutl[tid] = bout[tid];
  }
  __syncthreads();           // the ONLY wg-wide sync; waves decouple after this

  const int wv = tid >> 6, lane = tid & 63, lm = lane & 15, quad = lane >> 4;
  const int m0 = wv * 32;          // wave's private 32 batch rows (2 M-tiles)
  const bool hi = lm >= 8;
  const int j = lm & 7;            // this lane's j-column (0..7)
  const int mrow = m0 + (hi ? 16 : 0) + quad * 4;   // first of this lane's 4 rows

  // per-wave barrier flag block: 32 words (one per WG) for (cluster c, wave wv)
  unsigned* flg = (unsigned*)(ws + (size_t)c * 512 + (size_t)wv * 128);

  f32x4 pc[4];                     // prevC (4 rows x this lane's j), per layer
#pragma unroll
  for (int l = 0; l < 4; l++) pc[l] = zero_f4();

  f32x4 dc1 = zero_f4(), dc2 = zero_f4(), dc3 = zero_f4();

  auto arrive = [&](unsigned ep) {
    asm volatile("s_waitcnt vmcnt(0)" ::: "memory");   // publish stores in L2
    if (lane == 0)
      __hip_atomic_store(flg + g, ep, __ATOMIC_RELAXED, __HIP_MEMORY_SCOPE_AGENT);
  };
  auto waitbar = [&](unsigned ep) {
    asm volatile("" ::: "memory");
    for (;;) {
      unsigned v = __hip_atomic_load(flg + (lane & 31), __ATOMIC_RELAXED,
                                     __HIP_MEMORY_SCOPE_AGENT);
      if (__all((int)(v >= ep))) break;
    }
    asm volatile("buffer_inv sc0" ::: "memory");   // L1 invalidate (XCD acquire)
  };

  // ---- cell + publish from finished accumulators (gate exchange via DPP) ----
  auto cellpub = [&](auto Lc, int t, f32x4& A00, f32x4& A01, f32x4& A10, f32x4& A11) {
    constexpr int L = decltype(Lc)::value;
    constexpr int DL = DILa[L];
    constexpr int P = PERa[L];
    f32x4 s00, s01, s10, s11;
#pragma unroll
    for (int r = 0; r < 4; r++) {
      s00[r] = xor8_dpp(A00[r]);
      s01[r] = xor8_dpp(A01[r]);
      s10[r] = xor8_dpp(A10[r]);
      s11[r] = xor8_dpp(A11[r]);
    }
    f32x4 G0, G1, G2, G3;
#pragma unroll
    for (int r = 0; r < 4; r++) {
      G0[r] = hi ? s10[r] : A00[r];
      G1[r] = hi ? A10[r] : s00[r];
      G2[r] = hi ? s11[r] : A01[r];
      G3[r] = hi ? A11[r] : s01[r];
    }
    const f32x4 pcv = pc[L];
    f32x4 dC = zero_f4();
    if constexpr (L == 1) dC = dc1;
    if constexpr (L == 2) dC = dc2;
    if constexpr (L == 3) dC = dc3;
    f32x4 nC, wh;
#pragma unroll
    for (int q = 0; q < 4; q++) {
      const float fg = sigm(G0[q]);        // bias & +1.0 already in acc init
      const float cd = tanh_(G1[q]);
      const float og = sigm(G3[q]);
      float wc;
      if constexpr (L == 0) {
        wc = pcv[q];                       // dil=1: alpha*prevC+(1-alpha)*prevC
      } else {
        const float al = sigm(G2[q]);
        wc = (t >= DL) ? (al * pcv[q] + (1.0f - al) * dC[q]) : pcv[q];
      }
      const float nc = (t >= 1) ? (fg * wc + (1.0f - fg) * cd) : cd;
      nC[q] = nc;
      wh[q] = og * nc;
    }
    if constexpr (L == 1) *(f32x4*)(bufC1 + ((size_t)(t % 3) * 256 + tid) * 4) = nC;
    if constexpr (L == 2) *(f32x4*)(bufC2 + ((size_t)(t % 6) * 256 + tid) * 4) = nC;
    if constexpr (L == 3) *(f32x4*)(c3l + ((size_t)(t % 12) * 256 + tid) * 4) = nC;
    pc[L] = nC;
    const int jg = g * 8 + j;
#pragma unroll
    for (int r = 0; r < 4; r++) {
      const unsigned short us = f2bf(wh[r]);
      const int row = mrow + r;
      if (g < 16) outb[L][(size_t)row * OSW + jg] = us;
      else bufH[L][((size_t)(t % P) * ROWS + row) * HSW + (jg - 128)] = us;
    }
  };

  // ---- PRE (L in 1..3): acc init + non-ob segment MFMAs ----
  auto preL = [&](auto Lc, int t, f32x4& A00, f32x4& A01, f32x4& A10, f32x4& A11) {
    constexpr int L = decltype(Lc)::value;
    constexpr int NKT = KLa[L] / 32;
    constexpr int DL = DILa[L];
    constexpr int P = PERa[L];
    const unsigned short* wl = wlds + WOFFa[L];
    const float bb0 = biasl[L * 32 + lm] + (lm < 8 ? 1.0f : 0.0f);  // fg bias +1
    const float bb1 = biasl[L * 32 + 16 + lm];
    A00 = (f32x4){bb0, bb0, bb0, bb0};
    A10 = A00;
    A01 = (f32x4){bb1, bb1, bb1, bb1};
    A11 = A01;
    const unsigned short* phb =
        (t >= 1) ? bufH[L] + (size_t)((t - 1) % P) * ROWS * HSW : nullptr;
    const unsigned short* dhb =
        (t >= DL) ? bufH[L] + (size_t)((t - DL) % P) * ROWS * HSW : phb;
    const float* xb = x + ((size_t)t * BBATCH + (size_t)c * ROWS) * INW;
#pragma unroll
    for (int kt = 0; kt < NKT; kt++) {
      const int sty = seg_type(L, kt * 32);
      if (sty == 1) continue;                    // ob segments belong to POST
      const int sst = seg_start(L, kt * 32);
      const int kloc = kt * 32 - sst + quad * 8;
      short8 a0, a1;
      if (sty == 0) {
        const float* p = xb + (size_t)(m0 + lm) * INW + kloc;
        a0 = ld8f(p);
        a1 = ld8f(p + 16 * INW);
      } else {
        const unsigned short* sb = (sty == 2) ? phb : dhb;
        if (sb) {
          const unsigned short* p = sb + (size_t)(m0 + lm) * HSW + kloc;
          a0 = *(const short8*)p;
          a1 = *(const short8*)(p + 16 * HSW);
        } else {
          a0 = zero_s8();
          a1 = zero_s8();
        }
      }
      const short8 bf0v = *(const short8*)(wl + (kt * 2 + 0) * 512 + lm * 32 + quad * 8);
      const short8 bf1v = *(const short8*)(wl + (kt * 2 + 1) * 512 + lm * 32 + quad * 8);
      A00 = mfma16(a0, bf0v, A00);
      A01 = mfma16(a0, bf1v, A01);
      A10 = mfma16(a1, bf0v, A10);
      A11 = mfma16(a1, bf1v, A11);
    }
  };

  // ---- POST (L in 1..3): ob-segment MFMAs (kt 0..3) + cell + publish ----
  auto postL = [&](auto Lc, int t, f32x4& A00, f32x4& A01, f32x4& A10, f32x4& A11) {
    constexpr int L = decltype(Lc)::value;
    const unsigned short* wl = wlds + WOFFa[L];
    const unsigned short* ob = outb[L - 1];
#pragma unroll
    for (int kt = 0; kt < 4; kt++) {
      const int kloc = kt * 32 + quad * 8;
      const unsigned short* p = ob + (size_t)(m0 + lm) * HSW + kloc;
      const short8 a0 = *(const short8*)p;
      const short8 a1 = *(const short8*)(p + 16 * HSW);
      const short8 bf0v = *(const short8*)(wl + (kt * 2 + 0) * 512 + lm * 32 + quad * 8);
      const short8 bf1v = *(const short8*)(wl + (kt * 2 + 1) * 512 + lm * 32 + quad * 8);
      A00 = mfma16(a0, bf0v, A00);
      A01 = mfma16(a0, bf1v, A01);
      A10 = mfma16(a1, bf0v, A10);
      A11 = mfma16(a1, bf1v, A11);
    }
    cellpub(Lc, t, A00, A01, A10, A11);
  };

  // ---- full L0: no cross-WG same-step inputs; runs entirely in a window ----
  auto fullL0 = [&](int t) {
    if (t >= TT) return;
    f32x4 A00, A01, A10, A11;
    const unsigned short* wl = wlds + WOFFa[0];
    const float bb0 = biasl[lm] + (lm < 8 ? 1.0f : 0.0f);
    const float bb1 = biasl[16 + lm];
    A00 = (f32x4){bb0, bb0, bb0, bb0};
    A10 = A00;
    A01 = (f32x4){bb1, bb1, bb1, bb1};
    A11 = A01;
    const unsigned short* phb =
        (t >= 1) ? bufH[0] + (size_t)((t - 1) & 1) * ROWS * HSW : nullptr;
    const float* xb = x + ((size_t)t * BBATCH + (size_t)c * ROWS) * INW;
#pragma unroll
    for (int kt = 0; kt < 6; kt++) {
      const int sty = seg_type(0, kt * 32);
      const int sst = seg_start(0, kt * 32);
      const int kloc = kt * 32 - sst + quad * 8;
      short8 a0, a1;
      if (sty == 0) {
        const float* p = xb + (size_t)(m0 + lm) * INW + kloc;
        a0 = ld8f(p);
        a1 = ld8f(p + 16 * INW);
      } else if (phb) {
        const unsigned short* p = phb + (size_t)(m0 + lm) * HSW + kloc;
        a0 = *(const short8*)p;
        a1 = *(const short8*)(p + 16 * HSW);
      } else {
        a0 = zero_s8();
        a1 = zero_s8();
      }
      const short8 bf0v = *(const short8*)(wl + (kt * 2 + 0) * 512 + lm * 32 + quad * 8);
      const short8 bf1v = *(const short8*)(wl + (kt * 2 + 1) * 512 + lm * 32 + quad * 8);
      A00 = mfma16(a0, bf0v, A00);
      A01 = mfma16(a0, bf1v, A01);
      A10 = mfma16(a1, bf0v, A10);
      A11 = mfma16(a1, bf1v, A11);
    }
    cellpub(IC<0>{}, t, A00, A01, A10, A11);
  };

  // ---- fire-and-forget L2 touch of x(t): one dword per 128B line ----
  auto touchx = [&](int t) {
    if (t >= TT) return;
    const float* xt = x + ((size_t)t * BBATCH + (size_t)c * ROWS + m0) * INW
                      + (size_t)lane * 32;
    float tmp;
    asm volatile("global_load_dword %0, %1, off"
                 : "=v"(tmp) : "v"(xt) : "memory");
  };

  // ---- epilogue: wave computes y for its private row r = m0 + g ----
  auto epilogue = [&](int tt) {
    if (tt < 0) return;
    const int r = m0 + g;
    const unsigned short* orow = outb[3] + (size_t)r * OSW;
    const int o = lane >> 3, s = lane & 7;
    const short8 v0 = *(const short8*)(orow + s * 16);
    const short8 v1 = *(const short8*)(orow + s * 16 + 8);
    float part = 0.f;
#pragma unroll
    for (int i = 0; i < 8; i++)
      part += bf2f((unsigned short)v0[i]) * woutl[o * WSTR + s * 16 + i];
#pragma unroll
    for (int i = 0; i < 8; i++)
      part += bf2f((unsigned short)v1[i]) * woutl[o * WSTR + s * 16 + 8 + i];
    part += __shfl_down(part, 4);
    part += __shfl_down(part, 2);
    part += __shfl_down(part, 1);
    if (s == 0)
      yout[((size_t)tt * BBATCH + (size_t)c * ROWS + r) * NO + o] = part + boutl[o];
  };

  f32x4 a1_00, a1_01, a1_10, a1_11;    // L1 accumulators (windowA -> postB)
  f32x4 a2_00, a2_01, a2_10, a2_11;    // L2 accumulators (windowB -> postC)
  f32x4 a3_00, a3_01, a3_10, a3_11;    // L3 accumulators (windowC -> postA(t+1))

  // ---- main loop: 3 phases per step ----
  fullL0(0);                           // publishes L0(0); drains at arrive(1)
  unsigned ep = 0;
  for (int t = 0; t < TT; t++) {
    // === phase A: postL3(t-1) ===
    if (t > 0) postL(IC<3>{}, t - 1, a3_00, a3_01, a3_10, a3_11);
    arrive(++ep);
    preL(IC<1>{}, t, a1_00, a1_01, a1_10, a1_11);
    if (t >= 3) dc1 = *(const f32x4*)(bufC1 + ((size_t)(t % 3) * 256 + tid) * 4);
    waitbar(ep);
    // === phase B: postL1(t) ===
    postL(IC<1>{}, t, a1_00, a1_01, a1_10, a1_11);
    arrive(++ep);
    preL(IC<2>{}, t, a2_00, a2_01, a2_10, a2_11);
    if (t >= 6) dc2 = *(const f32x4*)(bufC2 + ((size_t)(t % 6) * 256 + tid) * 4);
    epilogue(t - 1);
    touchx(t + 2);
    waitbar(ep);
    // === phase C: postL2(t) ===
    postL(IC<2>{}, t, a2_00, a2_01, a2_10, a2_11);
    arrive(++ep);
    preL(IC<3>{}, t, a3_00, a3_01, a3_10, a3_11);
    if (t >= 12) dc3 = *(const f32x4*)(c3l + ((size_t)(t % 12) * 256 + tid) * 4);
    fullL0(t + 1);
    waitbar(ep);
  }
  // tail: finish L3(TT-1), then final epilogue
  postL(IC<3>{}, TT - 1, a3_00, a3_01, a3_10, a3_11);
  arrive(++ep);
  waitbar(ep);
  epilogue(TT - 1);
}

extern "C" void kernel_launch(void* const* d_in, const int* in_sizes, int n_in,
                              void* d_out, int out_size, void* d_ws, size_t ws_size,
                              hipStream_t stream) {
  const float* x    = (const float*)d_in[0];
  const float* W0   = (const float*)d_in[1];
  const float* b0   = (const float*)d_in[2];
  const float* W1   = (const float*)d_in[3];
  const float* b1   = (const float*)d_in[4];
  const float* W2   = (const float*)d_in[5];
  const float* b2   = (const float*)d_in[6];
  const float* W3   = (const float*)d_in[7];
  const float* b3   = (const float*)d_in[8];
  const float* Wout = (const float*)d_in[9];
  const float* bout = (const float*)d_in[10];
  float* out = (float*)d_out;
  char* ws = (char*)d_ws;

  if (ws_size < WS_NEED) {
    fprintf(stderr, "kernel_launch: ws_size %zu < needed %zu\n", ws_size, (size_t)WS_NEED);
    return;
  }

  // zero barrier flags + rank counters (ws is poisoned 0xAA before every launch)
  hipMemsetAsync(d_ws, 0, 8192, stream);

  hipError_t e = hipFuncSetAttribute((const void*)rnn_stack_kernel,
                                     hipFuncAttributeMaxDynamicSharedMemorySize,
                                     LDS_BYTES);
  if (e != hipSuccess) fprintf(stderr, "hipFuncSetAttribute: %d\n", (int)e);

  rnn_stack_kernel<<<dim3(256), dim3(256), LDS_BYTES, stream>>>(
      x, W0, b0, W1, b1, W2, b2, W3, b3, Wout, bout, out, ws);
  e = hipGetLastError();
  if (e != hipSuccess) fprintf(stderr, "launch error: %d\n", (int)e);
}

// Round 11
// 4217.044 us; speedup vs baseline: 1.1791x; 1.0338x over previous
//
#include <hip/hip_runtime.h>
#include <stdint.h>
#include <stdio.h>

// ---------------------------------------------------------------------------
// DilatedSparseRnnStack, round 15: r14 (green, 4359us) + within-phase load
// batching. Corrected counter model (r14): derived utils are ~4x inflated;
// real VALU ~5%, MFMA ~2% -> wave ~93% stalled, ~12k cy/phase. Cause: per-kt
// "if (sb)" branches + VGPR 132 stop the compiler from hoisting ring loads
// across kts -> one serialized L2 RTT per kt (~10 RTTs/window). Fix (zero
// barrier-relative movement => zero hazard; r9 proved the array machinery):
//  - preL/fullL0/postL are TWO-PASS: PASS1 issues all fragment loads into
//    named static arrays (x as raw f32; converted in PASS2), PASS2 = MFMAs.
//  - time loop split at t=13: FAST branch-free path for t>=13 (all ring
//    pointers valid), original branchy code for t<13.
// Also learned (r14): SQ_LDS_BANK_CONFLICT==2.517e7 is ~1/ds_read_b128
// (artifact of 1KB wave reads) -- not actionable; DPP exchange kept.
// Schedule per step t (3 barriers, r10):
//   A: postL3(t-1) | win: preL1(t) + dc1
//   B: postL1(t)   | win: preL2(t) + dc2 + epilogue(t-1) + touchx(t+2)
//   C: postL2(t)   | win: preL3(t) + dc3 + fullL0(t+1)
// ---------------------------------------------------------------------------

typedef __attribute__((ext_vector_type(8))) short short8;
typedef __attribute__((ext_vector_type(4))) float f32x4;

#define DEVINL static __device__ __forceinline__

constexpr int TT = 256, BBATCH = 1024, INW = 64, HSW = 128, OSW = 128, NO = 8;
constexpr int ROWS = 128;                 // batch rows per cluster

constexpr int KLa[4]   = {192, 384, 448, 384};   // layer-0 dH folded: 320 -> 192
constexpr int DILa[4]  = {1, 3, 6, 12};
constexpr int PERa[4]  = {2, 4, 7, 13};   // h ring period = dil+1
// tiled weight layout: per (kt, half) a 1KB tile of 512 ushorts [lm][quad][8]
constexpr int WOFFa[4] = {0, 6144, 18432, 32768};   // ushort offsets
constexpr int WBYTES   = 90112;                     // 32 rows x 1408 k x 2B

constexpr int BIAS_B  = WBYTES;                    // 90,112
constexpr int WOUT_B  = BIAS_B + 512;              // 90,624
constexpr int WSTR    = 129;                       // wout pad
constexpr int BOUT_B  = WOUT_B + 8 * WSTR * 4;     // 94,752
constexpr int C3_B    = BOUT_B + 32;               // 94,784
constexpr int LDS_BYTES = C3_B + 12 * 256 * 16;    // 143,936 (<= 160 KiB)

// workspace layout (bytes)
//   [0,4096)     barrier flags: cluster c, wave w -> ws + c*512 + w*128, 32 words
//   [4096,4608)  per-XCD rank counters (c*64)
constexpr size_t WSBASE    = 8192;
constexpr size_t BH_OFF[4] = {0, 65536, 196608, 425984}; // h rings (P_l slots of 128x128 bf16)
constexpr size_t OUTB_OFF  = 851968;                     // 4 x 128x128 bf16 (single-buffered)
constexpr size_t CB_OFF    = 983040;                     // C rings: layers 1,2
constexpr size_t C1_SZ     = 32 * 3 * 256 * 16;          // 393,216
constexpr size_t C2_SZ     = 32 * 6 * 256 * 16;          // 786,432
constexpr size_t CLSZ      = CB_OFF + C1_SZ + C2_SZ;     // 2,162,688 (~2.1 MB)
constexpr size_t WS_NEED   = WSBASE + 8 * CLSZ;          // ~17.3 MB

__host__ __device__ constexpr int seg_type(int L, int k) {
  // 0 = x (fp32), 1 = prev-layer out, 2 = prevH, 3 = dH
  if (L == 0) return k < 64 ? 0 : 2;                    // dH folded into prevH
  if (L == 1) return k < 128 ? 1 : (k < 256 ? 2 : 3);
  if (L == 2) return k < 128 ? 1 : (k < 192 ? 0 : (k < 320 ? 2 : 3));
  return k < 128 ? 1 : (k < 256 ? 2 : 3);
}
__host__ __device__ constexpr int seg_start(int L, int k) {
  if (L == 0) return k < 64 ? 0 : 64;
  if (L == 1) return k < 128 ? 0 : (k < 256 ? 128 : 256);
  if (L == 2) return k < 128 ? 0 : (k < 192 ? 128 : (k < 320 ? 192 : 320));
  return k < 128 ? 0 : (k < 256 ? 128 : 256);
}

template <int N> struct IC { static constexpr int value = N; };

DEVINL unsigned short f2bf(float f) {        // RNE fp32 -> bf16
  union { float f; uint32_t u; } v; v.f = f;
  return (unsigned short)((v.u + 0x7FFFu + ((v.u >> 16) & 1u)) >> 16);
}
DEVINL float bf2f(unsigned short h) {
  union { uint32_t u; float f; } v; v.u = ((uint32_t)h) << 16;
  return v.f;
}
DEVINL float sigm(float x)  { return 1.0f / (1.0f + __expf(-x)); }
DEVINL float tanh_(float x) { return 1.0f - 2.0f / (__expf(2.0f * x) + 1.0f); }

DEVINL short8 zero_s8() { short8 v; for (int i = 0; i < 8; i++) v[i] = 0; return v; }
DEVINL f32x4  zero_f4() { f32x4  v; for (int i = 0; i < 4; i++) v[i] = 0.f; return v; }

DEVINL f32x4 mfma16(short8 a, short8 b, f32x4 c) {
  return __builtin_amdgcn_mfma_f32_16x16x32_bf16(a, b, c, 0, 0, 0);
}

DEVINL short8 pk8(f32x4 a, f32x4 b) {        // 2x f32x4 -> bf16x8 fragment
  short8 r;
  r[0] = (short)f2bf(a[0]); r[1] = (short)f2bf(a[1]);
  r[2] = (short)f2bf(a[2]); r[3] = (short)f2bf(a[3]);
  r[4] = (short)f2bf(b[0]); r[5] = (short)f2bf(b[1]);
  r[6] = (short)f2bf(b[2]); r[7] = (short)f2bf(b[3]);
  return r;
}
DEVINL short8 ld8f(const float* p) {
  return pk8(*(const f32x4*)p, *(const f32x4*)(p + 4));
}

// lane ^ 8 exchange via DPP row_ror:8 (within each 16-lane row, (i+8)%16==i^8).
DEVINL float xor8_dpp(float v) {
  int i = __builtin_bit_cast(int, v);
  i = __builtin_amdgcn_mov_dpp(i, 0x128, 0xF, 0xF, false);   // row_ror:8
  return __builtin_bit_cast(float, i);
}

__global__ void __launch_bounds__(256, 1)
rnn_stack_kernel(const float* __restrict__ x,
                 const float* __restrict__ W0, const float* __restrict__ b0,
                 const float* __restrict__ W1, const float* __restrict__ b1,
                 const float* __restrict__ W2, const float* __restrict__ b2,
                 const float* __restrict__ W3, const float* __restrict__ b3,
                 const float* __restrict__ Wout, const float* __restrict__ bout,
                 float* __restrict__ yout, char* __restrict__ ws)
{
  extern __shared__ char smem[];
  unsigned short* wlds = (unsigned short*)smem;
  float* biasl = (float*)(smem + BIAS_B);
  float* woutl = (float*)(smem + WOUT_B);
  float* boutl = (float*)(smem + BOUT_B);
  float* c3l   = (float*)(smem + C3_B);     // [(slot*256 + tid)*4] f32 (lane-private)

  const int tid = threadIdx.x;

  // ---- runtime cluster formation: c = physical XCD, g = rank on that XCD ----
  __shared__ unsigned s_cg;
  if (tid == 0) {
    unsigned xcc;
    asm volatile("s_getreg_b32 %0, hwreg(HW_REG_XCC_ID)" : "=s"(xcc));
    xcc &= 7u;
    unsigned rank = __hip_atomic_fetch_add(
        (unsigned*)(ws + 4096 + (size_t)xcc * 64), 1u,
        __ATOMIC_RELAXED, __HIP_MEMORY_SCOPE_AGENT);
    s_cg = (xcc << 8) | (rank & 31u);
  }
  __syncthreads();
  const int c = __builtin_amdgcn_readfirstlane((int)(s_cg >> 8));
  const int g = __builtin_amdgcn_readfirstlane((int)(s_cg & 255));

  char* cb = ws + WSBASE + (size_t)c * CLSZ;
  unsigned short* bufH[4];
  unsigned short* outb[4];
#pragma unroll
  for (int l = 0; l < 4; l++) {
    bufH[l] = (unsigned short*)(cb + BH_OFF[l]);
    outb[l] = (unsigned short*)(cb + OUTB_OFF + (size_t)l * ROWS * OSW * 2);
  }
  float* bufC1 = (float*)(cb + CB_OFF + (size_t)g * (3 * 256 * 16));
  float* bufC2 = (float*)(cb + CB_OFF + C1_SZ + (size_t)g * (6 * 256 * 16));

  // ---- startup: weights -> tiled LDS (bf16); layer-0 dH block folded ----
  {
    const float* Wsrc[4] = {W0, W1, W2, W3};
    const float* bsrc[4] = {b0, b1, b2, b3};
    for (int l = 0; l < 4; l++) {
      const int K = KLa[l];
      const int Ksrc = (l == 0) ? 320 : K;             // W0 rows are length 320
      unsigned short* base = wlds + WOFFa[l];
      for (int n = 0; n < 32; n++) {
        const int grow = (n >> 3) * 256 + g * 8 + (n & 7);   // gate*SS + jglob
        const float* src = Wsrc[l] + (size_t)grow * Ksrc;
        for (int k = tid; k < K; k += 256) {
          float v = src[k];
          if (l == 0 && k >= 64) v += src[k + 128];    // fold W_dH into W_prevH
          base[((k >> 5) * 2 + (n >> 4)) * 512 + (n & 15) * 32 +
               ((k >> 3) & 3) * 8 + (k & 7)] = f2bf(v);
        }
      }
      if (tid < 32) biasl[l * 32 + tid] = bsrc[l][(tid >> 3) * 256 + g * 8 + (tid & 7)];
    }
    for (int i = tid; i < 8 * 128; i += 256) woutl[(i >> 7) * WSTR + (i & 127)] = Wout[i];
    if (tid < 8) boutl[tid] = bout[tid];
  }
  __syncthreads();           // the ONLY wg-wide sync; waves decouple after this

  const int wv = tid >> 6, lane = tid & 63, lm = lane & 15, quad = lane >> 4;
  const int m0 = wv * 32;          // wave's private 32 batch rows (2 M-tiles)
  const bool hi = lm >= 8;
  const int j = lm & 7;            // this lane's j-column (0..7)
  const int mrow = m0 + (hi ? 16 : 0) + quad * 4;   // first of this lane's 4 rows

  // per-wave barrier flag block: 32 words (one per WG) for (cluster c, wave wv)
  unsigned* flg = (unsigned*)(ws + (size_t)c * 512 + (size_t)wv * 128);

  f32x4 pc[4];                     // prevC (4 rows x this lane's j), per layer
#pragma unroll
  for (int l = 0; l < 4; l++) pc[l] = zero_f4();

  f32x4 dc1 = zero_f4(), dc2 = zero_f4(), dc3 = zero_f4();

  auto arrive = [&](unsigned ep) {
    asm volatile("s_waitcnt vmcnt(0)" ::: "memory");   // publish stores in L2
    if (lane == 0)
      __hip_atomic_store(flg + g, ep, __ATOMIC_RELAXED, __HIP_MEMORY_SCOPE_AGENT);
  };
  auto waitbar = [&](unsigned ep) {
    asm volatile("" ::: "memory");
    for (;;) {
      unsigned v = __hip_atomic_load(flg + (lane & 31), __ATOMIC_RELAXED,
                                     __HIP_MEMORY_SCOPE_AGENT);
      if (__all((int)(v >= ep))) break;
    }
    asm volatile("buffer_inv sc0" ::: "memory");   // L1 invalidate (XCD acquire)
  };

  // ---- cell + publish from finished accumulators (DPP gate exchange) ----
  auto cellpub = [&](auto Lc, int t, f32x4& A00, f32x4& A01, f32x4& A10, f32x4& A11) {
    constexpr int L = decltype(Lc)::value;
    constexpr int DL = DILa[L];
    constexpr int P = PERa[L];
    f32x4 s00, s01, s10, s11;
#pragma unroll
    for (int r = 0; r < 4; r++) {
      s00[r] = xor8_dpp(A00[r]);
      s01[r] = xor8_dpp(A01[r]);
      s10[r] = xor8_dpp(A10[r]);
      s11[r] = xor8_dpp(A11[r]);
    }
    f32x4 G0, G1, G2, G3;
#pragma unroll
    for (int r = 0; r < 4; r++) {
      G0[r] = hi ? s10[r] : A00[r];
      G1[r] = hi ? A10[r] : s00[r];
      G2[r] = hi ? s11[r] : A01[r];
      G3[r] = hi ? A11[r] : s01[r];
    }
    const f32x4 pcv = pc[L];
    f32x4 dC = zero_f4();
    if constexpr (L == 1) dC = dc1;
    if constexpr (L == 2) dC = dc2;
    if constexpr (L == 3) dC = dc3;
    f32x4 nC, wh;
#pragma unroll
    for (int q = 0; q < 4; q++) {
      const float fg = sigm(G0[q]);        // bias & +1.0 already in acc init
      const float cd = tanh_(G1[q]);
      const float og = sigm(G3[q]);
      float wc;
      if constexpr (L == 0) {
        wc = pcv[q];                       // dil=1: alpha*prevC+(1-alpha)*prevC
      } else {
        const float al = sigm(G2[q]);
        wc = (t >= DL) ? (al * pcv[q] + (1.0f - al) * dC[q]) : pcv[q];
      }
      const float nc = (t >= 1) ? (fg * wc + (1.0f - fg) * cd) : cd;
      nC[q] = nc;
      wh[q] = og * nc;
    }
    if constexpr (L == 1) *(f32x4*)(bufC1 + ((size_t)(t % 3) * 256 + tid) * 4) = nC;
    if constexpr (L == 2) *(f32x4*)(bufC2 + ((size_t)(t % 6) * 256 + tid) * 4) = nC;
    if constexpr (L == 3) *(f32x4*)(c3l + ((size_t)(t % 12) * 256 + tid) * 4) = nC;
    pc[L] = nC;
    const int jg = g * 8 + j;
#pragma unroll
    for (int r = 0; r < 4; r++) {
      const unsigned short us = f2bf(wh[r]);
      const int row = mrow + r;
      if (g < 16) outb[L][(size_t)row * OSW + jg] = us;
      else bufH[L][((size_t)(t % P) * ROWS + row) * HSW + (jg - 128)] = us;
    }
  };

  // ---- PRE (L in 1..3): acc init + non-ob segment MFMAs.
  //      FAST: branch-free two-pass (all loads batched, then MFMAs). ----
  auto preL = [&](auto Lc, auto Fc, int t,
                  f32x4& A00, f32x4& A01, f32x4& A10, f32x4& A11) {
    constexpr int L = decltype(Lc)::value;
    constexpr bool FAST = decltype(Fc)::value;
    constexpr int NKT = KLa[L] / 32;
    constexpr int DL = DILa[L];
    constexpr int P = PERa[L];
    const unsigned short* wl = wlds + WOFFa[L];
    const float bb0 = biasl[L * 32 + lm] + (lm < 8 ? 1.0f : 0.0f);  // fg bias +1
    const float bb1 = biasl[L * 32 + 16 + lm];
    A00 = (f32x4){bb0, bb0, bb0, bb0};
    A10 = A00;
    A01 = (f32x4){bb1, bb1, bb1, bb1};
    A11 = A01;
    const float* xb = x + ((size_t)t * BBATCH + (size_t)c * ROWS) * INW;
    if constexpr (FAST) {
      const unsigned short* phb = bufH[L] + (size_t)((t - 1) % P) * ROWS * HSW;
      const unsigned short* dhb = bufH[L] + (size_t)((t - DL) % P) * ROWS * HSW;
      constexpr int NK2 = NKT - 4;           // non-ob kts (4..NKT-1)
      short8 a0v[NK2], a1v[NK2];
      f32x4 xr[8];                           // raw x (L2 only: kts 4,5)
      // PASS1: batch-issue every load (no branches; sty folds at compile time)
#pragma unroll
      for (int i = 0; i < NK2; i++) {
        const int kt = 4 + i;
        const int sty = seg_type(L, kt * 32);
        const int sst = seg_start(L, kt * 32);
        const int kloc = kt * 32 - sst + quad * 8;
        if (sty == 0) {
          const float* p = xb + (size_t)(m0 + lm) * INW + kloc;
          xr[i * 4 + 0] = *(const f32x4*)p;
          xr[i * 4 + 1] = *(const f32x4*)(p + 4);
          const float* q2 = p + 16 * INW;
          xr[i * 4 + 2] = *(const f32x4*)q2;
          xr[i * 4 + 3] = *(const f32x4*)(q2 + 4);
        } else {
          const unsigned short* sb = (sty == 2) ? phb : dhb;
          const unsigned short* p = sb + (size_t)(m0 + lm) * HSW + kloc;
          a0v[i] = *(const short8*)p;
          a1v[i] = *(const short8*)(p + 16 * HSW);
        }
      }
      // PASS2: MFMA chain (converts x in-place)
#pragma unroll
      for (int i = 0; i < NK2; i++) {
        const int kt = 4 + i;
        const int sty = seg_type(L, kt * 32);
        short8 a0, a1;
        if (sty == 0) {
          a0 = pk8(xr[i * 4 + 0], xr[i * 4 + 1]);
          a1 = pk8(xr[i * 4 + 2], xr[i * 4 + 3]);
        } else {
          a0 = a0v[i];
          a1 = a1v[i];
        }
        const short8 bf0v = *(const short8*)(wl + (kt * 2 + 0) * 512 + lm * 32 + quad * 8);
        const short8 bf1v = *(const short8*)(wl + (kt * 2 + 1) * 512 + lm * 32 + quad * 8);
        A00 = mfma16(a0, bf0v, A00);
        A01 = mfma16(a0, bf1v, A01);
        A10 = mfma16(a1, bf0v, A10);
        A11 = mfma16(a1, bf1v, A11);
      }
    } else {
      const unsigned short* phb =
          (t >= 1) ? bufH[L] + (size_t)((t - 1) % P) * ROWS * HSW : nullptr;
      const unsigned short* dhb =
          (t >= DL) ? bufH[L] + (size_t)((t - DL) % P) * ROWS * HSW : phb;
#pragma unroll
      for (int kt = 0; kt < NKT; kt++) {
        const int sty = seg_type(L, kt * 32);
        if (sty == 1) continue;                    // ob segments belong to POST
        const int sst = seg_start(L, kt * 32);
        const int kloc = kt * 32 - sst + quad * 8;
        short8 a0, a1;
        if (sty == 0) {
          const float* p = xb + (size_t)(m0 + lm) * INW + kloc;
          a0 = ld8f(p);
          a1 = ld8f(p + 16 * INW);
        } else {
          const unsigned short* sb = (sty == 2) ? phb : dhb;
          if (sb) {
            const unsigned short* p = sb + (size_t)(m0 + lm) * HSW + kloc;
            a0 = *(const short8*)p;
            a1 = *(const short8*)(p + 16 * HSW);
          } else {
            a0 = zero_s8();
            a1 = zero_s8();
          }
        }
        const short8 bf0v = *(const short8*)(wl + (kt * 2 + 0) * 512 + lm * 32 + quad * 8);
        const short8 bf1v = *(const short8*)(wl + (kt * 2 + 1) * 512 + lm * 32 + quad * 8);
        A00 = mfma16(a0, bf0v, A00);
        A01 = mfma16(a0, bf1v, A01);
        A10 = mfma16(a1, bf0v, A10);
        A11 = mfma16(a1, bf1v, A11);
      }
    }
  };

  // ---- POST (L in 1..3): two-pass ob loads + MFMAs + cell + publish ----
  auto postL = [&](auto Lc, int t, f32x4& A00, f32x4& A01, f32x4& A10, f32x4& A11) {
    constexpr int L = decltype(Lc)::value;
    const unsigned short* wl = wlds + WOFFa[L];
    const unsigned short* ob = outb[L - 1];
    short8 o0[4], o1[4];
#pragma unroll
    for (int kt = 0; kt < 4; kt++) {
      const unsigned short* p = ob + (size_t)(m0 + lm) * HSW + kt * 32 + quad * 8;
      o0[kt] = *(const short8*)p;
      o1[kt] = *(const short8*)(p + 16 * HSW);
    }
#pragma unroll
    for (int kt = 0; kt < 4; kt++) {
      const short8 bf0v = *(const short8*)(wl + (kt * 2 + 0) * 512 + lm * 32 + quad * 8);
      const short8 bf1v = *(const short8*)(wl + (kt * 2 + 1) * 512 + lm * 32 + quad * 8);
      A00 = mfma16(o0[kt], bf0v, A00);
      A01 = mfma16(o0[kt], bf1v, A01);
      A10 = mfma16(o1[kt], bf0v, A10);
      A11 = mfma16(o1[kt], bf1v, A11);
    }
    cellpub(Lc, t, A00, A01, A10, A11);
  };

  // ---- full L0 (window C): FAST = two-pass branch-free (needs t>=1) ----
  auto fullL0 = [&](auto Fc, int t) {
    if (t >= TT) return;
    constexpr bool FAST = decltype(Fc)::value;
    f32x4 A00, A01, A10, A11;
    const unsigned short* wl = wlds + WOFFa[0];
    const float bb0 = biasl[lm] + (lm < 8 ? 1.0f : 0.0f);
    const float bb1 = biasl[16 + lm];
    A00 = (f32x4){bb0, bb0, bb0, bb0};
    A10 = A00;
    A01 = (f32x4){bb1, bb1, bb1, bb1};
    A11 = A01;
    const float* xb = x + ((size_t)t * BBATCH + (size_t)c * ROWS) * INW;
    if constexpr (FAST) {
      const unsigned short* phb = bufH[0] + (size_t)((t - 1) & 1) * ROWS * HSW;
      f32x4 xr[8];                 // kts 0..1 raw x (2 kts x 2 tiles x 2 regs)
      short8 h0[4], h1[4];         // kts 2..5 prevH
#pragma unroll
      for (int kt = 0; kt < 2; kt++) {
        const float* p = xb + (size_t)(m0 + lm) * INW + kt * 32 + quad * 8;
        xr[kt * 4 + 0] = *(const f32x4*)p;
        xr[kt * 4 + 1] = *(const f32x4*)(p + 4);
        const float* q2 = p + 16 * INW;
        xr[kt * 4 + 2] = *(const f32x4*)q2;
        xr[kt * 4 + 3] = *(const f32x4*)(q2 + 4);
      }
#pragma unroll
      for (int i = 0; i < 4; i++) {
        const int kloc = i * 32 + quad * 8;        // h cols 0..127
        const unsigned short* p = phb + (size_t)(m0 + lm) * HSW + kloc;
        h0[i] = *(const short8*)p;
        h1[i] = *(const short8*)(p + 16 * HSW);
      }
#pragma unroll
      for (int kt = 0; kt < 6; kt++) {
        short8 a0, a1;
        if (kt < 2) {
          a0 = pk8(xr[kt * 4 + 0], xr[kt * 4 + 1]);
          a1 = pk8(xr[kt * 4 + 2], xr[kt * 4 + 3]);
        } else {
          a0 = h0[kt - 2];
          a1 = h1[kt - 2];
        }
        const short8 bf0v = *(const short8*)(wl + (kt * 2 + 0) * 512 + lm * 32 + quad * 8);
        const short8 bf1v = *(const short8*)(wl + (kt * 2 + 1) * 512 + lm * 32 + quad * 8);
        A00 = mfma16(a0, bf0v, A00);
        A01 = mfma16(a0, bf1v, A01);
        A10 = mfma16(a1, bf0v, A10);
        A11 = mfma16(a1, bf1v, A11);
      }
    } else {
      const unsigned short* phb =
          (t >= 1) ? bufH[0] + (size_t)((t - 1) & 1) * ROWS * HSW : nullptr;
#pragma unroll
      for (int kt = 0; kt < 6; kt++) {
        const int sty = seg_type(0, kt * 32);
        const int sst = seg_start(0, kt * 32);
        const int kloc = kt * 32 - sst + quad * 8;
        short8 a0, a1;
        if (sty == 0) {
          const float* p = xb + (size_t)(m0 + lm) * INW + kloc;
          a0 = ld8f(p);
          a1 = ld8f(p + 16 * INW);
        } else if (phb) {
          const unsigned short* p = phb + (size_t)(m0 + lm) * HSW + kloc;
          a0 = *(const short8*)p;
          a1 = *(const short8*)(p + 16 * HSW);
        } else {
          a0 = zero_s8();
          a1 = zero_s8();
        }
        const short8 bf0v = *(const short8*)(wl + (kt * 2 + 0) * 512 + lm * 32 + quad * 8);
        const short8 bf1v = *(const short8*)(wl + (kt * 2 + 1) * 512 + lm * 32 + quad * 8);
        A00 = mfma16(a0, bf0v, A00);
        A01 = mfma16(a0, bf1v, A01);
        A10 = mfma16(a1, bf0v, A10);
        A11 = mfma16(a1, bf1v, A11);
      }
    }
    cellpub(IC<0>{}, t, A00, A01, A10, A11);
  };

  // ---- fire-and-forget L2 touch of x(t): one dword per 128B line ----
  auto touchx = [&](int t) {
    if (t >= TT) return;
    const float* xt = x + ((size_t)t * BBATCH + (size_t)c * ROWS + m0) * INW
                      + (size_t)lane * 32;
    float tmp;
    asm volatile("global_load_dword %0, %1, off"
                 : "=v"(tmp) : "v"(xt) : "memory");
  };

  // ---- epilogue: wave computes y for its private row r = m0 + g ----
  auto epilogue = [&](int tt) {
    if (tt < 0) return;
    const int r = m0 + g;
    const unsigned short* orow = outb[3] + (size_t)r * OSW;
    const int o = lane >> 3, s = lane & 7;
    const short8 v0 = *(const short8*)(orow + s * 16);
    const short8 v1 = *(const short8*)(orow + s * 16 + 8);
    float part = 0.f;
#pragma unroll
    for (int i = 0; i < 8; i++)
      part += bf2f((unsigned short)v0[i]) * woutl[o * WSTR + s * 16 + i];
#pragma unroll
    for (int i = 0; i < 8; i++)
      part += bf2f((unsigned short)v1[i]) * woutl[o * WSTR + s * 16 + 8 + i];
    part += __shfl_down(part, 4);
    part += __shfl_down(part, 2);
    part += __shfl_down(part, 1);
    if (s == 0)
      yout[((size_t)tt * BBATCH + (size_t)c * ROWS + r) * NO + o] = part + boutl[o];
  };

  f32x4 a1_00, a1_01, a1_10, a1_11;    // L1 accumulators (windowA -> postB)
  f32x4 a2_00, a2_01, a2_10, a2_11;    // L2 accumulators (windowB -> postC)
  f32x4 a3_00, a3_01, a3_10, a3_11;    // L3 accumulators (windowC -> postA(t+1))

  unsigned ep = 0;

  // one full step (3 phases); Fc selects branch-free FAST bodies (t>=13)
  auto stepT = [&](auto Fc, int t) {
    constexpr bool FAST = decltype(Fc)::value;
    // === phase A: postL3(t-1) ===
    if (t > 0) postL(IC<3>{}, t - 1, a3_00, a3_01, a3_10, a3_11);
    arrive(++ep);
    preL(IC<1>{}, Fc, t, a1_00, a1_01, a1_10, a1_11);
    if (FAST || t >= 3) dc1 = *(const f32x4*)(bufC1 + ((size_t)(t % 3) * 256 + tid) * 4);
    waitbar(ep);
    // === phase B: postL1(t) ===
    postL(IC<1>{}, t, a1_00, a1_01, a1_10, a1_11);
    arrive(++ep);
    preL(IC<2>{}, Fc, t, a2_00, a2_01, a2_10, a2_11);
    if (FAST || t >= 6) dc2 = *(const f32x4*)(bufC2 + ((size_t)(t % 6) * 256 + tid) * 4);
    epilogue(t - 1);
    touchx(t + 2);
    waitbar(ep);
    // === phase C: postL2(t) ===
    postL(IC<2>{}, t, a2_00, a2_01, a2_10, a2_11);
    arrive(++ep);
    preL(IC<3>{}, Fc, t, a3_00, a3_01, a3_10, a3_11);
    if (FAST || t >= 12) dc3 = *(const f32x4*)(c3l + ((size_t)(t % 12) * 256 + tid) * 4);
    fullL0(IC<1>{}, t + 1);          // t+1 >= 1 always inside the loop
    waitbar(ep);
  };

  // ---- main: slow (branchy) warmup steps, then branch-free fast steps ----
  fullL0(IC<0>{}, 0);                // t=0: phb invalid -> slow body
  for (int t = 0; t < 13; t++) stepT(IC<0>{}, t);
  for (int t = 13; t < TT; t++) stepT(IC<1>{}, t);

  // tail: finish L3(TT-1), then final epilogue
  postL(IC<3>{}, TT - 1, a3_00, a3_01, a3_10, a3_11);
  arrive(++ep);
  waitbar(ep);
  epilogue(TT - 1);
}

extern "C" void kernel_launch(void* const* d_in, const int* in_sizes, int n_in,
                              void* d_out, int out_size, void* d_ws, size_t ws_size,
                              hipStream_t stream) {
  const float* x    = (const float*)d_in[0];
  const float* W0   = (const float*)d_in[1];
  const float* b0   = (const float*)d_in[2];
  const float* W1   = (const float*)d_in[3];
  const float* b1   = (const float*)d_in[4];
  const float* W2   = (const float*)d_in[5];
  const float* b2   = (const float*)d_in[6];
  const float* W3   = (const float*)d_in[7];
  const float* b3   = (const float*)d_in[8];
  const float* Wout = (const float*)d_in[9];
  const float* bout = (const float*)d_in[10];
  float* out = (float*)d_out;
  char* ws = (char*)d_ws;

  if (ws_size < WS_NEED) {
    fprintf(stderr, "kernel_launch: ws_size %zu < needed %zu\n", ws_size, (size_t)WS_NEED);
    return;
  }

  // zero barrier flags + rank counters (ws is poisoned 0xAA before every launch)
  hipMemsetAsync(d_ws, 0, 8192, stream);

  hipError_t e = hipFuncSetAttribute((const void*)rnn_stack_kernel,
                                     hipFuncAttributeMaxDynamicSharedMemorySize,
                                     LDS_BYTES);
  if (e != hipSuccess) fprintf(stderr, "hipFuncSetAttribute: %d\n", (int)e);

  rnn_stack_kernel<<<dim3(256), dim3(256), LDS_BYTES, stream>>>(
      x, W0, b0, W1, b1, W2, b2, W3, b3, Wout, bout, out, ws);
  e = hipGetLastError();
  if (e != hipSuccess) fprintf(stderr, "launch error: %d\n", (int)e);
}